// Round 1
// baseline (898.068 us; speedup 1.0000x reference)
//
#include <hip/hip_runtime.h>
#include <hip/hip_bf16.h>

#define N_NODES 100000
#define N_EDGES 3200000
#define D 64
#define NEG_SLOPE 0.01f

// ---------------- CSR build ----------------

__global__ __launch_bounds__(256) void hist_k(const int* __restrict__ dst, int* __restrict__ degi) {
    int e = blockIdx.x * 256 + threadIdx.x;
    if (e < N_EDGES) atomicAdd(&degi[dst[e]], 1);
}

// per-wave exclusive scan + one atomic per wave to allocate contiguous CSR ranges
// (range order across waves is arbitrary — aggregation only needs grouping, not order)
__global__ __launch_bounds__(256) void scan_k(const int* __restrict__ degi, float* __restrict__ rsd,
                                              int* __restrict__ offs, int* __restrict__ counter) {
    int i = blockIdx.x * 256 + threadIdx.x;
    int lane = threadIdx.x & 63;
    int d = (i < N_NODES) ? degi[i] : 0;
    if (i < N_NODES) rsd[i] = rsqrtf((float)(d > 0 ? d : 1));
    int incl = d;
    #pragma unroll
    for (int o = 1; o < 64; o <<= 1) {
        int v = __shfl_up(incl, o, 64);
        if (lane >= o) incl += v;
    }
    int total = __shfl(incl, 63, 64);
    int base = 0;
    if (lane == 63) base = atomicAdd(counter, total);
    base = __shfl(base, 63, 64);
    if (i < N_NODES) offs[i] = base + incl - d;
}

__global__ __launch_bounds__(256) void fill_k(const int* __restrict__ src, const int* __restrict__ dst,
                                              const int* __restrict__ offs, int* __restrict__ fillc,
                                              int* __restrict__ csr_src) {
    int e = blockIdx.x * 256 + threadIdx.x;
    if (e < N_EDGES) {
        int di = dst[e];
        int p = atomicAdd(&fillc[di], 1);
        csr_src[offs[di] + p] = src[e];
    }
}

// ---------------- per-layer: weighted neighbor sum ----------------
// s[i,:] = rsd[i] * sum_{j in N(i)} rsd[j] * in[j,:]
// one wave per node, lane = feature dim -> every gather is a coalesced 256B read
__global__ __launch_bounds__(256) void agg_k(const float* __restrict__ in, int stride,
                                             const float* __restrict__ rsd,
                                             const int* __restrict__ offs, const int* __restrict__ degi,
                                             const int* __restrict__ csr_src, float* __restrict__ s) {
    int node = blockIdx.x * 4 + (threadIdx.x >> 6);
    int lane = threadIdx.x & 63;
    if (node >= N_NODES) return;
    int start = offs[node];
    int deg = degi[node];
    float acc = 0.f;
    int j = 0;
    for (; j + 4 <= deg; j += 4) {
        int s0 = csr_src[start + j + 0];
        int s1 = csr_src[start + j + 1];
        int s2 = csr_src[start + j + 2];
        int s3 = csr_src[start + j + 3];
        float r0 = rsd[s0], r1 = rsd[s1], r2 = rsd[s2], r3 = rsd[s3];
        float x0 = in[(size_t)s0 * stride + lane];
        float x1 = in[(size_t)s1 * stride + lane];
        float x2 = in[(size_t)s2 * stride + lane];
        float x3 = in[(size_t)s3 * stride + lane];
        acc += r0 * x0;
        acc += r1 * x1;
        acc += r2 * x2;
        acc += r3 * x3;
    }
    for (; j < deg; ++j) {
        int sj = csr_src[start + j];
        acc += rsd[sj] * in[(size_t)sj * stride + lane];
    }
    s[node * D + lane] = rsd[node] * acc;
}

// ---------------- per-layer: combine + GEMM ----------------
// out[n, cOff + d] = act( (in[n]+s[n]) @ W1 + (s[n]*in[n]) @ W2 )
// W1,W2 staged in LDS; wave handles 4 nodes: m = lane>>4 picks node, lane&15 picks
// 4-column strip -> all LDS reads are b128, W rows conflict-free (2 lanes/bank).
__global__ __launch_bounds__(256) void comb_k(const float* __restrict__ in, int stride,
                                              const float* __restrict__ s,
                                              const float* __restrict__ W1, const float* __restrict__ W2,
                                              float* __restrict__ out, int act) {
    __shared__ float W1s[D * D];
    __shared__ float W2s[D * D];
    __shared__ float aL[4][4][D];   // [wave][m][k]
    __shared__ float bL[4][4][D];
    int tid = threadIdx.x;
    {
        const float4* w1v = (const float4*)W1;
        const float4* w2v = (const float4*)W2;
        float4* w1s = (float4*)W1s;
        float4* w2s = (float4*)W2s;
        for (int t = tid; t < D * D / 4; t += 256) { w1s[t] = w1v[t]; w2s[t] = w2v[t]; }
    }
    int w = tid >> 6;
    int l = tid & 63;
    int m = l >> 4;
    int cb = (l & 15) * 4;
    __syncthreads();
    for (int it = 0; it < 2; ++it) {
        int n0 = blockIdx.x * 32 + it * 16 + w * 4;
        #pragma unroll
        for (int mm = 0; mm < 4; ++mm) {
            float xv = in[(size_t)(n0 + mm) * stride + l];
            float sp = s[(size_t)(n0 + mm) * D + l];
            aL[w][mm][l] = xv + sp;
            bL[w][mm][l] = sp * xv;
        }
        __syncthreads();   // orders the cross-lane LDS write->read (also stops compiler reorder)
        float acc0 = 0.f, acc1 = 0.f, acc2 = 0.f, acc3 = 0.f;
        const float4* aV = (const float4*)&aL[w][m][0];
        const float4* bV = (const float4*)&bL[w][m][0];
        #pragma unroll
        for (int kk = 0; kk < 16; ++kk) {
            float4 a4 = aV[kk];
            float4 b4 = bV[kk];
            #pragma unroll
            for (int j = 0; j < 4; ++j) {
                int k = kk * 4 + j;
                float aj = (j == 0) ? a4.x : (j == 1) ? a4.y : (j == 2) ? a4.z : a4.w;
                float bj = (j == 0) ? b4.x : (j == 1) ? b4.y : (j == 2) ? b4.z : b4.w;
                float4 w1 = *(const float4*)&W1s[k * D + cb];
                float4 w2 = *(const float4*)&W2s[k * D + cb];
                acc0 += aj * w1.x + bj * w2.x;
                acc1 += aj * w1.y + bj * w2.y;
                acc2 += aj * w1.z + bj * w2.z;
                acc3 += aj * w1.w + bj * w2.w;
            }
        }
        int n = n0 + m;
        float4 r;
        r.x = acc0; r.y = acc1; r.z = acc2; r.w = acc3;
        if (act) {
            r.x = r.x >= 0.f ? r.x : NEG_SLOPE * r.x;
            r.y = r.y >= 0.f ? r.y : NEG_SLOPE * r.y;
            r.z = r.z >= 0.f ? r.z : NEG_SLOPE * r.z;
            r.w = r.w >= 0.f ? r.w : NEG_SLOPE * r.w;
        }
        *(float4*)&out[(size_t)n * 192 + cb] = r;
        __syncthreads();   // WAR guard before next iteration's aL/bL writes
    }
}

extern "C" void kernel_launch(void* const* d_in, const int* in_sizes, int n_in,
                              void* d_out, int out_size, void* d_ws, size_t ws_size,
                              hipStream_t stream) {
    const float* x   = (const float*)d_in[0];
    const float* W1a = (const float*)d_in[1];
    const float* W2a = (const float*)d_in[2];
    const float* W1b = (const float*)d_in[3];
    const float* W2b = (const float*)d_in[4];
    const int*   src = (const int*)d_in[5];
    const int*   dst = (const int*)d_in[6];
    float* out = (float*)d_out;

    // workspace layout (~40 MB)
    int*   degi    = (int*)d_ws;            // N
    int*   fillc   = degi + N_NODES;        // N
    int*   offs    = fillc + N_NODES;       // N
    float* rsd     = (float*)(offs + N_NODES); // N
    int*   counter = (int*)(rsd + N_NODES); // 1 (padded to 64)
    int*   csr_src = counter + 64;          // E
    float* s       = (float*)(csr_src + N_EDGES); // N*D

    hipMemsetAsync(degi, 0, 2 * N_NODES * sizeof(int), stream);  // degi + fillc
    hipMemsetAsync(counter, 0, sizeof(int), stream);

    int eb = (N_EDGES + 255) / 256;
    int nb = (N_NODES + 255) / 256;
    hist_k<<<eb, 256, 0, stream>>>(dst, degi);
    scan_k<<<nb, 256, 0, stream>>>(degi, rsd, offs, counter);
    fill_k<<<eb, 256, 0, stream>>>(src, dst, offs, fillc, csr_src);

    int ab = (N_NODES + 3) / 4;   // 25000, one wave per node
    int cbg = N_NODES / 32;       // 3125, exact (100000 = 3125*32)

    // layer 1: h1 = lrelu(conv(x, W1a, W2a)) -> out cols [0,64)
    agg_k<<<ab, 256, 0, stream>>>(x, D, rsd, offs, degi, csr_src, s);
    comb_k<<<cbg, 256, 0, stream>>>(x, D, s, W1a, W2a, out + 0, 1);
    // layer 2: h2 = lrelu(conv(h1, W1b, W2b)) -> out cols [64,128)
    agg_k<<<ab, 256, 0, stream>>>(out + 0, 192, rsd, offs, degi, csr_src, s);
    comb_k<<<cbg, 256, 0, stream>>>(out + 0, 192, s, W1b, W2b, out + 64, 1);
    // layer 3: h3 = conv(h2, W1b, W2b) (no act) -> out cols [128,192)
    agg_k<<<ab, 256, 0, stream>>>(out + 64, 192, rsd, offs, degi, csr_src, s);
    comb_k<<<cbg, 256, 0, stream>>>(out + 64, 192, s, W1b, W2b, out + 128, 0);
}